// Round 4
// baseline (226.044 us; speedup 1.0000x reference)
//
#include <hip/hip_runtime.h>
#include <stdint.h>

// ReviewLoss: ce[i] = logsumexp(out[i,:]) - out[i, target[i]]
//   lam = k-th (0-indexed, descending) order statistic of ce, k = int(N*0.3)
//   result = mean over ALL N of (ce >= lam ? ce : 0)
//
// R3 post-mortem: block-per-row ce (2 barriers + 4KB in flight per block,
// 32768 WGs) ran ~3x over the BW roofline. This version: ONE WAVE PER ROW,
// four explicitly-named float4 regs (no indexed array -> no scratch
// demotion, the R1 bug), zero LDS, zero barriers, shuffle-only reductions.
// 4 KB in flight per wave x 32 waves/CU = 128 KB/CU.
// select_kernel (radix select on IEEE bits + filtered mean) unchanged.

typedef unsigned int uint32;

__global__ __launch_bounds__(256) void ce_kernel(
    const float* __restrict__ logits, const int* __restrict__ target,
    float* __restrict__ ce, int N, int C) {
  const int lane = (int)(threadIdx.x & 63);
  const int row = (int)((blockIdx.x * blockDim.x + threadIdx.x) >> 6);
  if (row >= N) return;

  const float* rp = logits + (size_t)row * (size_t)C;

  // Uniform per-wave loads (broadcast), issued early.
  const int t = target[row];
  const float ot = rp[t];

  const float4* rp4 = (const float4*)rp;
  const int nv4 = C >> 2;  // C % 4 == 0 (C=1000 -> 250 quads)
  const float4 NEG = make_float4(-INFINITY, -INFINITY, -INFINITY, -INFINITY);

  // Four explicitly-named quads: lane + {0,64,128,192}. Covers C <= 1024.
  float4 v0 = (lane       < nv4) ? rp4[lane      ] : NEG;
  float4 v1 = (lane +  64 < nv4) ? rp4[lane +  64] : NEG;
  float4 v2 = (lane + 128 < nv4) ? rp4[lane + 128] : NEG;
  float4 v3 = (lane + 192 < nv4) ? rp4[lane + 192] : NEG;

  // Wave max (no LDS, no barrier)
  float m = fmaxf(fmaxf(fmaxf(v0.x, v0.y), fmaxf(v0.z, v0.w)),
                  fmaxf(fmaxf(fmaxf(v1.x, v1.y), fmaxf(v1.z, v1.w)),
                        fmaxf(fmaxf(fmaxf(v2.x, v2.y), fmaxf(v2.z, v2.w)),
                              fmaxf(fmaxf(v3.x, v3.y), fmaxf(v3.z, v3.w)))));
#pragma unroll
  for (int off = 1; off < 64; off <<= 1) m = fmaxf(m, __shfl_xor(m, off));

  // Sum of exp(x - m) on the still-held registers; -inf pads -> 0
  float e = __expf(v0.x - m) + __expf(v0.y - m) + __expf(v0.z - m) + __expf(v0.w - m)
          + __expf(v1.x - m) + __expf(v1.y - m) + __expf(v1.z - m) + __expf(v1.w - m)
          + __expf(v2.x - m) + __expf(v2.y - m) + __expf(v2.z - m) + __expf(v2.w - m)
          + __expf(v3.x - m) + __expf(v3.y - m) + __expf(v3.z - m) + __expf(v3.w - m);
#pragma unroll
  for (int off = 1; off < 64; off <<= 1) e += __shfl_xor(e, off);

  if (lane == 0) {
    float cev = (m - ot) + __logf(e);
    ce[row] = fmaxf(cev, 0.0f);  // ce >= 0 analytically; kill -0.0
  }
}

// Wave-aggregated histogram add: one LDS atomic per DISTINCT bin per wave.
// All 64 lanes must be active (uniform control flow).
__device__ __forceinline__ void wave_hist_add(uint32* h, uint32 bin, int lane) {
  bool done = false;
  while (true) {
    unsigned long long pend = __ballot(!done);
    if (pend == 0ull) break;
    int src = (int)__ffsll((unsigned long long)pend) - 1;
    uint32 b = (uint32)__shfl((int)bin, src);
    bool mine = (!done) && (bin == b);
    unsigned long long m = __ballot(mine);
    if (lane == src) atomicAdd(&h[b], (uint32)__popcll(m));
    if (mine) done = true;
  }
}

// Inclusive suffix sum over s[0..n) (n <= 2048), 1024 threads, in place.
// Caller must __syncthreads() before calling.
__device__ __forceinline__ void suffix_scan(uint32* s, int n, int tid) {
  for (int off = 1; off < n; off <<= 1) {
    uint32 a = 0, b = 0;
    int i0 = tid, i1 = tid + 1024;
    if (i0 < n) a = s[i0] + ((i0 + off < n) ? s[i0 + off] : 0u);
    if (i1 < n) b = s[i1] + ((i1 + off < n) ? s[i1 + off] : 0u);
    __syncthreads();
    if (i0 < n) s[i0] = a;
    if (i1 < n) s[i1] = b;
    __syncthreads();
  }
}

__global__ __launch_bounds__(1024) void select_kernel(
    const float* __restrict__ ce, float* __restrict__ out, int N, int k) {
  __shared__ uint32 s[2048];
  __shared__ uint32 sel[2];
  __shared__ double wsum[16];
  const int tid = (int)threadIdx.x;
  const int lane = tid & 63;
  const uint32 kk0 = (uint32)k;
  const float4* ce4 = (const float4*)ce;
  const int N4 = N >> 2;  // N % 4 == 0

  // ---- Level 1: top 11 bits; wave-aggregated LDS atomics (hot bins!) ----
  s[tid] = 0; s[tid + 1024] = 0;
  __syncthreads();
  for (int i = tid; i < N4; i += 1024) {
    float4 x = ce4[i];
    wave_hist_add(s, __float_as_uint(x.x) >> 21, lane);
    wave_hist_add(s, __float_as_uint(x.y) >> 21, lane);
    wave_hist_add(s, __float_as_uint(x.z) >> 21, lane);
    wave_hist_add(s, __float_as_uint(x.w) >> 21, lane);
  }
  __syncthreads();
  suffix_scan(s, 2048, tid);
  for (int i = tid; i < 2048; i += 1024) {
    uint32 SG = (i + 1 < 2048) ? s[i + 1] : 0u;  // count strictly greater
    if (SG <= kk0 && kk0 < s[i]) { sel[0] = (uint32)i; sel[1] = kk0 - SG; }
  }
  __syncthreads();
  const uint32 B1 = sel[0];
  const uint32 k1 = sel[1];
  __syncthreads();

  // ---- Level 2: bits 20..10 (mantissa bits: well-spread, plain atomics) ----
  s[tid] = 0; s[tid + 1024] = 0;
  __syncthreads();
  for (int i = tid; i < N4; i += 1024) {
    float4 x = ce4[i];
    uint32 u0 = __float_as_uint(x.x), u1 = __float_as_uint(x.y);
    uint32 u2 = __float_as_uint(x.z), u3 = __float_as_uint(x.w);
    if ((u0 >> 21) == B1) atomicAdd(&s[(u0 >> 10) & 2047u], 1u);
    if ((u1 >> 21) == B1) atomicAdd(&s[(u1 >> 10) & 2047u], 1u);
    if ((u2 >> 21) == B1) atomicAdd(&s[(u2 >> 10) & 2047u], 1u);
    if ((u3 >> 21) == B1) atomicAdd(&s[(u3 >> 10) & 2047u], 1u);
  }
  __syncthreads();
  suffix_scan(s, 2048, tid);
  for (int i = tid; i < 2048; i += 1024) {
    uint32 SG = (i + 1 < 2048) ? s[i + 1] : 0u;
    if (SG <= k1 && k1 < s[i]) { sel[0] = (uint32)i; sel[1] = k1 - SG; }
  }
  __syncthreads();
  const uint32 B2 = sel[0];
  const uint32 k2 = sel[1];
  __syncthreads();

  // ---- Level 3: bits 9..0 ----
  s[tid] = 0;
  __syncthreads();
  const uint32 pre = (B1 << 11) | B2;
  for (int i = tid; i < N4; i += 1024) {
    float4 x = ce4[i];
    uint32 u0 = __float_as_uint(x.x), u1 = __float_as_uint(x.y);
    uint32 u2 = __float_as_uint(x.z), u3 = __float_as_uint(x.w);
    if ((u0 >> 10) == pre) atomicAdd(&s[u0 & 1023u], 1u);
    if ((u1 >> 10) == pre) atomicAdd(&s[u1 & 1023u], 1u);
    if ((u2 >> 10) == pre) atomicAdd(&s[u2 & 1023u], 1u);
    if ((u3 >> 10) == pre) atomicAdd(&s[u3 & 1023u], 1u);
  }
  __syncthreads();
  suffix_scan(s, 1024, tid);
  {
    int i = tid;  // 1024 bins, 1024 threads
    uint32 SG = (i + 1 < 1024) ? s[i + 1] : 0u;
    if (SG <= k2 && k2 < s[i]) sel[0] = (uint32)i;
  }
  __syncthreads();
  const uint32 lam_u = (pre << 10) | sel[0];

  // ---- Sum of all ce >= lam (bit order == value order for ce >= 0) ----
  double acc = 0.0;
  for (int i = tid; i < N4; i += 1024) {
    float4 x = ce4[i];
    if (__float_as_uint(x.x) >= lam_u) acc += (double)x.x;
    if (__float_as_uint(x.y) >= lam_u) acc += (double)x.y;
    if (__float_as_uint(x.z) >= lam_u) acc += (double)x.z;
    if (__float_as_uint(x.w) >= lam_u) acc += (double)x.w;
  }
#pragma unroll
  for (int off = 1; off < 64; off <<= 1) acc += __shfl_xor(acc, off);
  if ((tid & 63) == 0) wsum[tid >> 6] = acc;
  __syncthreads();
  if (tid == 0) {
    double tsum = 0.0;
    for (int i = 0; i < 16; ++i) tsum += wsum[i];
    out[0] = (float)(tsum / (double)N);
  }
}

extern "C" void kernel_launch(void* const* d_in, const int* in_sizes, int n_in,
                              void* d_out, int out_size, void* d_ws, size_t ws_size,
                              hipStream_t stream) {
  const float* logits = (const float*)d_in[0];
  const int* target = (const int*)d_in[1];
  float* out = (float*)d_out;

  const int N = in_sizes[1];            // 32768
  const int C = in_sizes[0] / N;        // 1000

  float* ce = (float*)d_ws;

  // Kernel 1: one WAVE per row, 4 rows per 256-thread block.
  int grid = (N + 3) / 4;
  ce_kernel<<<grid, 256, 0, stream>>>(logits, target, ce, N, C);

  // k = int(N * 0.3)
  int k = (int)((double)N * 0.3);

  // Kernel 2: single block: histogram + radix refine + filtered mean.
  select_kernel<<<1, 1024, 0, stream>>>(ce, out, N, k);
}

// Round 5
// 214.221 us; speedup vs baseline: 1.0552x; 1.0552x over previous
//
#include <hip/hip_runtime.h>
#include <stdint.h>

// ReviewLoss: ce[i] = logsumexp(out[i,:]) - out[i, target[i]]
//   lam = k-th (0-indexed, descending) order statistic of ce, k = int(N*0.3)
//   result = mean over ALL N of (ce >= lam ? ce : 0)
//
// R4 post-mortem: totals R3 (block-per-row ce) == R4 (wave-per-row ce)
// ==> budget decomposition: OH(harness fills/restore) ~115us, ce ~50us,
// select ~50us. select did FOUR single-CU grid-stride passes over the
// 128 KB ce array (~13us each, latency-bound cross-XCD reads) plus a
// ballot-loop histogram. This version: TWO global passes.
//   Pass 1: full-resolution 16384-bin histogram of key = u>>17 (packed
//     uint16 pairs in uint32, counts<=N<65536 so no carry), plain LDS
//     atomics (fine-grained bins -> low multiplicity, no hot bins).
//     Hierarchical suffix scan finds lambda's 14-bit key K + rank k'.
//   Pass 2: sum all key>K (double), collect key==K candidates into LDS
//     (reuse hist space); resolve lambda's exact 32 bits among candidates
//     by rank-counting; add candidates >= lambda. One reduce, done.

typedef unsigned int uint32;

__global__ __launch_bounds__(256) void ce_kernel(
    const float* __restrict__ logits, const int* __restrict__ target,
    float* __restrict__ ce, int N, int C) {
  const int lane = (int)(threadIdx.x & 63);
  const int row = (int)((blockIdx.x * blockDim.x + threadIdx.x) >> 6);
  if (row >= N) return;

  const float* rp = logits + (size_t)row * (size_t)C;

  // Uniform per-wave loads (broadcast), issued early.
  const int t = target[row];
  const float ot = rp[t];

  const float4* rp4 = (const float4*)rp;
  const int nv4 = C >> 2;  // C % 4 == 0 (C=1000 -> 250 quads)
  const float4 NEG = make_float4(-INFINITY, -INFINITY, -INFINITY, -INFINITY);

  // Four explicitly-named quads: lane + {0,64,128,192}. Covers C <= 1024.
  float4 v0 = (lane       < nv4) ? rp4[lane      ] : NEG;
  float4 v1 = (lane +  64 < nv4) ? rp4[lane +  64] : NEG;
  float4 v2 = (lane + 128 < nv4) ? rp4[lane + 128] : NEG;
  float4 v3 = (lane + 192 < nv4) ? rp4[lane + 192] : NEG;

  // Wave max (no LDS, no barrier)
  float m = fmaxf(fmaxf(fmaxf(v0.x, v0.y), fmaxf(v0.z, v0.w)),
                  fmaxf(fmaxf(fmaxf(v1.x, v1.y), fmaxf(v1.z, v1.w)),
                        fmaxf(fmaxf(fmaxf(v2.x, v2.y), fmaxf(v2.z, v2.w)),
                              fmaxf(fmaxf(v3.x, v3.y), fmaxf(v3.z, v3.w)))));
#pragma unroll
  for (int off = 1; off < 64; off <<= 1) m = fmaxf(m, __shfl_xor(m, off));

  // Sum of exp(x - m) on the still-held registers; -inf pads -> 0
  float e = __expf(v0.x - m) + __expf(v0.y - m) + __expf(v0.z - m) + __expf(v0.w - m)
          + __expf(v1.x - m) + __expf(v1.y - m) + __expf(v1.z - m) + __expf(v1.w - m)
          + __expf(v2.x - m) + __expf(v2.y - m) + __expf(v2.z - m) + __expf(v2.w - m)
          + __expf(v3.x - m) + __expf(v3.y - m) + __expf(v3.z - m) + __expf(v3.w - m);
#pragma unroll
  for (int off = 1; off < 64; off <<= 1) e += __shfl_xor(e, off);

  if (lane == 0) {
    float cev = (m - ot) + __logf(e);
    ce[row] = fmaxf(cev, 0.0f);  // ce >= 0 analytically; kill -0.0
  }
}

// Packed 16-bit count access: bin b lives in h[b>>1], low half if b even.
__device__ __forceinline__ uint32 bin_count(const uint32* h, uint32 b) {
  uint32 w = h[b >> 1];
  return (b & 1u) ? (w >> 16) : (w & 0xFFFFu);
}

__global__ __launch_bounds__(1024) void select_kernel(
    const float* __restrict__ ce, float* __restrict__ out, int N, int k) {
  __shared__ uint32 h[8192];    // 16384 packed uint16 bins; reused as cand list
  __shared__ uint32 g[1024];    // group suffix sums
  __shared__ uint32 sel[4];     // [0]=K, [1]=k', [2]=lam_u
  __shared__ uint32 candcnt;
  __shared__ double wsum[16];
  const int tid = (int)threadIdx.x;
  const float4* ce4 = (const float4*)ce;
  const int N4 = N >> 2;  // N % 4 == 0
  const uint32 kk = (uint32)k;

  // ---- Zero histogram ----
#pragma unroll
  for (int j = 0; j < 8; ++j) h[tid + 1024 * j] = 0;
  __syncthreads();

  // ---- Pass 1: 16384-bin histogram of key = u >> 17 ----
  for (int i = tid; i < N4; i += 1024) {
    float4 x = ce4[i];
    uint32 k0 = __float_as_uint(x.x) >> 17;
    uint32 k1 = __float_as_uint(x.y) >> 17;
    uint32 k2 = __float_as_uint(x.z) >> 17;
    uint32 k3 = __float_as_uint(x.w) >> 17;
    atomicAdd(&h[k0 >> 1], (k0 & 1u) ? 0x10000u : 1u);
    atomicAdd(&h[k1 >> 1], (k1 & 1u) ? 0x10000u : 1u);
    atomicAdd(&h[k2 >> 1], (k2 & 1u) ? 0x10000u : 1u);
    atomicAdd(&h[k3 >> 1], (k3 & 1u) ? 0x10000u : 1u);
  }
  __syncthreads();

  // ---- Group sums: thread t covers bins [16t, 16t+16) = words [8t, 8t+8) ----
  {
    uint32 c = 0;
#pragma unroll
    for (int j = 0; j < 8; ++j) {
      uint32 w = h[8 * tid + j];
      c += (w & 0xFFFFu) + (w >> 16);
    }
    g[tid] = c;
  }
  __syncthreads();

  // ---- Inclusive suffix scan over g[1024]: g[t] = count(group >= t) ----
  for (int off = 1; off < 1024; off <<= 1) {
    uint32 val = g[tid] + ((tid + off < 1024) ? g[tid + off] : 0u);
    __syncthreads();
    g[tid] = val;
    __syncthreads();
  }

  // ---- Find group t*: count(group > t*) <= k < count(group >= t*) ----
  {
    uint32 SG = (tid + 1 < 1024) ? g[tid + 1] : 0u;
    if (SG <= kk && kk < g[tid]) { sel[0] = (uint32)tid; sel[1] = kk - SG; }
  }
  __syncthreads();

  // ---- Walk the 16 bins of group t* from the top ----
  if (tid == 0) {
    uint32 grp = sel[0];
    uint32 kg = sel[1];
    uint32 acc = 0;
    for (int b = 15; b >= 0; --b) {
      uint32 bin = grp * 16u + (uint32)b;
      uint32 c = bin_count(h, bin);
      if (kg < acc + c) { sel[0] = bin; sel[1] = kg - acc; break; }
      acc += c;
    }
    candcnt = 0;
  }
  __syncthreads();
  const uint32 K = sel[0];       // lambda's 14-bit key
  const uint32 kprime = sel[1];  // rank within bin K (descending)
  __syncthreads();               // everyone has K before h is reused

  // ---- Pass 2: sum key > K; collect key == K candidates into h ----
  double acc = 0.0;
  for (int i = tid; i < N4; i += 1024) {
    float4 x = ce4[i];
    uint32 u0 = __float_as_uint(x.x), u1 = __float_as_uint(x.y);
    uint32 u2 = __float_as_uint(x.z), u3 = __float_as_uint(x.w);
    if ((u0 >> 17) > K) acc += (double)x.x;
    else if ((u0 >> 17) == K) { uint32 p = atomicAdd(&candcnt, 1u); if (p < 8192u) h[p] = u0; }
    if ((u1 >> 17) > K) acc += (double)x.y;
    else if ((u1 >> 17) == K) { uint32 p = atomicAdd(&candcnt, 1u); if (p < 8192u) h[p] = u1; }
    if ((u2 >> 17) > K) acc += (double)x.z;
    else if ((u2 >> 17) == K) { uint32 p = atomicAdd(&candcnt, 1u); if (p < 8192u) h[p] = u2; }
    if ((u3 >> 17) > K) acc += (double)x.w;
    else if ((u3 >> 17) == K) { uint32 p = atomicAdd(&candcnt, 1u); if (p < 8192u) h[p] = u3; }
  }
  __syncthreads();

  // ---- Resolve lambda's exact bits among candidates (rank k' descending) ----
  const uint32 c = (candcnt < 8192u) ? candcnt : 8192u;
  for (uint32 j = (uint32)tid; j < c; j += 1024u) {
    uint32 uj = h[j];
    uint32 grt = 0, eq = 0;
    for (uint32 l = 0; l < c; ++l) {
      uint32 v = h[l];
      grt += (v > uj) ? 1u : 0u;
      eq += (v == uj) ? 1u : 0u;
    }
    if (grt <= kprime && kprime < grt + eq) sel[2] = uj;  // benign same-value race
  }
  __syncthreads();
  const uint32 lam_u = sel[2];

  // ---- Add candidates >= lambda ----
  for (uint32 j = (uint32)tid; j < c; j += 1024u) {
    uint32 uj = h[j];
    if (uj >= lam_u) acc += (double)__uint_as_float(uj);
  }

  // ---- Reduce and write mean ----
#pragma unroll
  for (int off = 1; off < 64; off <<= 1) acc += __shfl_xor(acc, off);
  if ((tid & 63) == 0) wsum[tid >> 6] = acc;
  __syncthreads();
  if (tid == 0) {
    double tsum = 0.0;
    for (int i = 0; i < 16; ++i) tsum += wsum[i];
    out[0] = (float)(tsum / (double)N);
  }
}

extern "C" void kernel_launch(void* const* d_in, const int* in_sizes, int n_in,
                              void* d_out, int out_size, void* d_ws, size_t ws_size,
                              hipStream_t stream) {
  const float* logits = (const float*)d_in[0];
  const int* target = (const int*)d_in[1];
  float* out = (float*)d_out;

  const int N = in_sizes[1];            // 32768
  const int C = in_sizes[0] / N;        // 1000

  float* ce = (float*)d_ws;

  // Kernel 1: one WAVE per row, 4 rows per 256-thread block.
  int grid = (N + 3) / 4;
  ce_kernel<<<grid, 256, 0, stream>>>(logits, target, ce, N, C);

  // k = int(N * 0.3)
  int k = (int)((double)N * 0.3);

  // Kernel 2: single block, 2 global passes: hist+select, sum+resolve.
  select_kernel<<<1, 1024, 0, stream>>>(ce, out, N, k);
}